// Round 9
// baseline (5793.522 us; speedup 1.0000x reference)
//
#include <hip/hip_runtime.h>
#include <hip/hip_bf16.h>

// SentenceClassifier: LSTM(B=64,T=512,E=512,H=1024) -> h_T @ outW + outb -> softmax/CE
// Persistent-kernel, 128 blocks x 256 thr, block owns 8 hidden units (32 gate
// cols, W slice 96KB LDS). R9: ZERO-FLAG SENTINEL PROTOCOL. Rotating h buffers
// are pre-filled with bf16-NaN sentinel words (0x7FC07FC0 -- unreachable by
// f2bf of finite values); each address only ever transitions sentinel->data
// (4B-atomic stores), so the DATA carries readiness. Producers fire agent-
// scope write-through stores and move on (no vmcnt ack, no flag). Consumers
// burst 32x16B NONTEMPORAL loads (no L2 allocate -> no stale lines, always
// LLC-fresh), sentinel-check each chunk, and retry missing chunks with
// targeted agent-scope 8B loads + s_sleep backoff. Collapses the 4 serialized
// LLC rounds/step (store-ack, flag, poll-detect, load) to 2 and deletes the
// poll request storm. kk order unchanged (bit-identical numerics).

#define Bb 64
#define Tt 512
#define Ee 512
#define Hh 1024
#define Cc 32
#define G4 4096
#define NKS 48     // (E+H)/32
#define NBLK 128
#define HIDB 8     // hid units per block
#define SENTW 0x7FC07FC0u   // 2x bf16 NaN -- sentinel word

typedef __attribute__((ext_vector_type(8))) short short8;
typedef __attribute__((ext_vector_type(4))) float f32x4;

__device__ __forceinline__ unsigned short f2bf(float f) {
  __hip_bfloat16 h = __float2bfloat16(f);
  union { __hip_bfloat16 h; unsigned short u; } cv; cv.h = h; return cv.u;
}
static __device__ __forceinline__ float fsig(float x) { return 1.0f / (1.0f + __expf(-x)); }
static __device__ __forceinline__ float ftanhf(float x) {
  float e = __expf(-2.0f * fabsf(x));
  float t = (1.0f - e) / (1.0f + e);
  return copysignf(t, x);
}

// ---- x [B,T,E] f32 -> xT [T,B,E] bf16 (contiguous 64KB window per step) ----
__global__ __launch_bounds__(256) void transpose_x_kernel(const float* __restrict__ x,
                                                          unsigned short* __restrict__ xT) {
  const int bid = blockIdx.x;          // row*Tt + t
  const int row = bid >> 9, t = bid & (Tt - 1);
  const int e = threadIdx.x * 2;
  const float* src = x + ((size_t)row * Tt + t) * Ee + e;
  float2 v = *(const float2*)src;
  ushort2 o; o.x = f2bf(v.x); o.y = f2bf(v.y);
  *(ushort2*)(xT + ((size_t)t * Bb + row) * Ee + e) = o;
}

// ---- W [1536,4096] f32 -> per-block B-frag-packed bf16 --------------------
__global__ __launch_bounds__(64) void pack_w_kernel(const float* __restrict__ W,
                                                    unsigned short* __restrict__ Wpk) {
  const int fid = blockIdx.x;          // blk*96 + tau*48 + ks
  const int l = threadIdx.x;
  const int blk = fid / 96, rem = fid % 96;
  const int tau = rem / 48, ks = rem % 48;
  const int c = l & 15;
  const int col = (2 * tau + (c >> 3)) * Hh + blk * HIDB + (c & 7);
  const int k0 = ks * 32 + (l >> 4) * 8;
  short8 v;
#pragma unroll
  for (int i = 0; i < 8; i++) v[i] = (short)f2bf(W[(size_t)(k0 + i) * G4 + col]);
  *(short8*)(Wpk + ((size_t)fid * 64 + l) * 8) = v;
}

// ---- pre-fill all h buffers with sentinel ---------------------------------
__global__ __launch_bounds__(256) void fill_sentinel_kernel(uint4* __restrict__ p, long n4) {
  long i = (long)blockIdx.x * 256 + threadIdx.x;
  const long stride = (long)gridDim.x * 256;
  uint4 v; v.x = SENTW; v.y = SENTW; v.z = SENTW; v.w = SENTW;
  for (; i < n4; i += stride) p[i] = v;
}

// ---- zero h buffer 0 (t=0 input: h=0) -------------------------------------
__global__ __launch_bounds__(256) void zero_h0_kernel(uint4* __restrict__ p) {
  int i = blockIdx.x * 256 + threadIdx.x;   // grid covers Bb*Hh*2/16
  uint4 z; z.x = 0; z.y = 0; z.z = 0; z.w = 0;
  p[i] = z;
}

// ---- persistent LSTM kernel ----------------------------------------------
__global__ __launch_bounds__(256, 1) void lstm_persist(
    const unsigned short* __restrict__ xT, const unsigned short* __restrict__ Wpk,
    const float* __restrict__ bias,
    unsigned short* __restrict__ hseq,   // Tt buffers, block-major [bc][row][8hid]
    float* __restrict__ h_f32) {
  __shared__ short8 Wl[2 * NKS * 64];       // 96 KiB
  const int bc = blockIdx.x;
  const int tid = threadIdx.x;

  { // one-time: W slice -> LDS (linear 96KB copy)
    const short8* src = (const short8*)Wpk + (size_t)bc * (2 * NKS * 64);
    for (int i = tid; i < 2 * NKS * 64; i += 256) Wl[i] = src[i];
  }

  const int wv = tid >> 6, ln = tid & 63;
  const int c = ln & 15, kg = ln >> 4;
  const int arow = wv * 16 + c;        // A-frag row = batch index
  const int rbase = wv * 16 + kg * 4;  // D rows (m89 layout: row=(l>>4)*4+r, col=l&15)
  const int hid = bc * HIDB + (c & 7);
  const bool lo = (c < 8);
  const float bi = bias[hid], bj = bias[Hh + hid];
  const float bff = bias[2 * Hh + hid], bo = bias[3 * Hh + hid];
  float cstate[4] = {0.f, 0.f, 0.f, 0.f};

  __syncthreads();                      // W in LDS ready (only barrier in kernel)

  const short8* W0 = Wl;                // tile0 (gates i,j)
  const short8* W1 = Wl + NKS * 64;     // tile1 (gates f,o)

  // x-part W fragments: same LDS addresses every step -> hoist to registers
  short8 wx0[16], wx1[16];
#pragma unroll
  for (int kk = 0; kk < 16; kk++) { wx0[kk] = W0[kk * 64 + ln]; wx1[kk] = W1[kk * 64 + ln]; }

  f32x4 xa0, xa1;
  // x-part for t=0
  {
    const unsigned short* xr = xT + ((size_t)0 * Bb + arow) * Ee + kg * 8;
    f32x4 a0 = {0.f,0.f,0.f,0.f}, a1 = {0.f,0.f,0.f,0.f};
#pragma unroll
    for (int kk = 0; kk < 16; kk++) {
      short8 a = *(const short8*)(xr + kk * 32);
      a0 = __builtin_amdgcn_mfma_f32_16x16x32_bf16(a, wx0[kk], a0, 0, 0, 0);
      a1 = __builtin_amdgcn_mfma_f32_16x16x32_bf16(a, wx1[kk], a1, 0, 0, 0);
    }
    xa0 = a0; xa1 = a1;
  }

  for (int t = 0; t < Tt; t++) {
    // ---- nontemporal burst: 32 independent 16B h-loads (no L2 allocate ->
    // always LLC-fresh; staleness structurally impossible). Then sentinel
    // check; retry missing chunks with agent-scope 8B loads + backoff.
    const unsigned short* hr = hseq + (size_t)t * (NBLK * Bb * HIDB) + kg * 512 + arow * 8;
    short8 f[32];
#pragma unroll
    for (int kk = 0; kk < 32; kk++)
      f[kk] = __builtin_nontemporal_load((const short8*)(hr + kk * 2048));
    asm volatile("s_waitcnt vmcnt(0)" ::: "memory");
    __builtin_amdgcn_sched_barrier(0);

    unsigned miss = 0;
#pragma unroll
    for (int kk = 0; kk < 32; kk++) {
      union { short8 s; unsigned u[4]; } q; q.s = f[kk];
      if ((q.u[0] == SENTW) | (q.u[1] == SENTW) | (q.u[2] == SENTW) | (q.u[3] == SENTW))
        miss |= (1u << kk);
    }
    while (__any(miss)) {
      __builtin_amdgcn_s_sleep(2);
#pragma unroll
      for (int kk = 0; kk < 32; kk++) {
        if (miss & (1u << kk)) {
          const unsigned long long* pq = (const unsigned long long*)(hr + kk * 2048);
          unsigned long long w0 = __hip_atomic_load(pq,     __ATOMIC_RELAXED, __HIP_MEMORY_SCOPE_AGENT);
          unsigned long long w1 = __hip_atomic_load(pq + 1, __ATOMIC_RELAXED, __HIP_MEMORY_SCOPE_AGENT);
          union { unsigned long long q[2]; short8 s; unsigned u[4]; } nb;
          nb.q[0] = w0; nb.q[1] = w1;
          if (!((nb.u[0] == SENTW) | (nb.u[1] == SENTW) |
                (nb.u[2] == SENTW) | (nb.u[3] == SENTW))) {
            f[kk] = nb.s;
            miss &= ~(1u << kk);
          }
        }
      }
    }

    f32x4 a0 = xa0, a1 = xa1;
#pragma unroll
    for (int kk = 0; kk < 32; kk++) {
      a0 = __builtin_amdgcn_mfma_f32_16x16x32_bf16(f[kk], W0[(16 + kk) * 64 + ln], a0, 0, 0, 0);
      a1 = __builtin_amdgcn_mfma_f32_16x16x32_bf16(f[kk], W1[(16 + kk) * 64 + ln], a1, 0, 0, 0);
    }

    // cell update: tile0 lane c<8 holds i (c>=8: j), tile1 holds f (o). One
    // shfl_xor(8) gives each lane all 4 gates; lane pair (c, c^8) redundant.
    float hnew[4];
#pragma unroll
    for (int r = 0; r < 4; r++) {
      const float p0 = a0[r], p1 = a1[r];
      const float s0 = __shfl_xor(p0, 8), s1 = __shfl_xor(p1, 8);
      const float gi = (lo ? p0 : s0) + bi;
      const float gj = (lo ? s0 : p0) + bj;
      const float gf = (lo ? p1 : s1) + bff;
      const float go = (lo ? s1 : p1) + bo;
      const float cn = cstate[r] * fsig(gf + 1.0f) + fsig(gi) * ftanhf(gj);
      cstate[r] = cn;
      hnew[r] = ftanhf(cn) * fsig(go);
    }

    if (t < Tt - 1) {
      // pack hid pairs into 4B words; even-lo lanes store agent-coherent
      // (write-through). Fire-and-forget: consumers validate via sentinel.
      unsigned int hw[4];
#pragma unroll
      for (int r = 0; r < 4; r++) {
        unsigned short us = f2bf(hnew[r]);
        unsigned short ps = (unsigned short)__shfl_xor((int)us, 1);
        hw[r] = (unsigned)us | ((unsigned)ps << 16);
      }
      unsigned int* hob = (unsigned int*)hseq + (size_t)(t + 1) * (NBLK * Bb * HIDB / 2)
                          + bc * (Bb * HIDB / 2);
      if (lo && !(c & 1)) {
#pragma unroll
        for (int r = 0; r < 4; r++)
          __hip_atomic_store(hob + (rbase + r) * 4 + ((c & 7) >> 1),
                             hw[r], __ATOMIC_RELAXED, __HIP_MEMORY_SCOPE_AGENT);
      }
      // x-part MFMAs for t+1 (h-independent, W from registers) -- runs while
      // our stores fly to the LLC; no ack, no flag.
      {
        const unsigned short* xr = xT + ((size_t)(t + 1) * Bb + arow) * Ee + kg * 8;
        f32x4 b0 = {0.f,0.f,0.f,0.f}, b1 = {0.f,0.f,0.f,0.f};
#pragma unroll
        for (int kk = 0; kk < 16; kk++) {
          short8 a = *(const short8*)(xr + kk * 32);
          b0 = __builtin_amdgcn_mfma_f32_16x16x32_bf16(a, wx0[kk], b0, 0, 0, 0);
          b1 = __builtin_amdgcn_mfma_f32_16x16x32_bf16(a, wx1[kk], b1, 0, 0, 0);
        }
        xa0 = b0; xa1 = b1;
      }
    } else {
      if (lo) {
#pragma unroll
        for (int r = 0; r < 4; r++) h_f32[(rbase + r) * Hh + hid] = hnew[r];
      }
    }
  }
}

// ---- classifier: pred = h @ outW + outb, softmax, per-row CE --------------
__global__ __launch_bounds__(256) void classifier_kernel(
    const float* __restrict__ h, const float* __restrict__ outW,
    const float* __restrict__ outb, const float* __restrict__ y,
    float* __restrict__ out, float* __restrict__ losses) {
  __shared__ float red[256];
  const int brow = blockIdx.x;
  const int tid = threadIdx.x;
  const int cc = tid & 31;
  const int part = tid >> 5;
  const float* hr = h + brow * Hh;
  float p = 0.f;
  for (int k = part * 128; k < part * 128 + 128; k++)
    p += hr[k] * outW[k * Cc + cc];
  red[tid] = p;
  __syncthreads();
  if (part < 4) red[tid] += red[tid + 128];
  __syncthreads();
  if (part < 2) red[tid] += red[tid + 64];
  __syncthreads();
  if (part < 1) red[tid] += red[tid + 32];
  __syncthreads();
  if (tid < 32) {
    const float logit = red[tid] + outb[tid];
    float m = logit;
    for (int off = 16; off >= 1; off >>= 1) m = fmaxf(m, __shfl_xor(m, off));
    const float e = __expf(logit - m);
    float s = e;
    for (int off = 16; off >= 1; off >>= 1) s += __shfl_xor(s, off);
    out[brow * Cc + tid] = logit;
    out[Bb * Cc + brow * Cc + tid] = e / s;
    const float logp = (logit - m) - __logf(s);
    float contrib = y[brow * Cc + tid] * logp;
    for (int off = 16; off >= 1; off >>= 1) contrib += __shfl_xor(contrib, off);
    if (tid == 0) losses[brow] = -contrib;
  }
}

__global__ __launch_bounds__(64) void finalize_kernel(const float* __restrict__ losses,
                                                      float* __restrict__ out) {
  float v = losses[threadIdx.x];
  for (int off = 32; off >= 1; off >>= 1) v += __shfl_down(v, off);
  if (threadIdx.x == 0) out[2 * Bb * Cc] = v * (1.0f / Bb);
}

extern "C" void kernel_launch(void* const* d_in, const int* in_sizes, int n_in,
                              void* d_out, int out_size, void* d_ws, size_t ws_size,
                              hipStream_t stream) {
  const float* x    = (const float*)d_in[0];
  const float* y    = (const float*)d_in[1];
  // d_in[2] = seqlen (unused)
  const float* W    = (const float*)d_in[3];
  const float* bias = (const float*)d_in[4];
  const float* outW = (const float*)d_in[5];
  const float* outb = (const float*)d_in[6];
  float* out = (float*)d_out;

  char* wsp = (char*)d_ws;
  size_t off = 0;
  auto walloc = [&](size_t bytes) -> void* {
    void* p = wsp + off;
    off += (bytes + 255) & ~(size_t)255;
    return p;
  };
  unsigned short* xT   = (unsigned short*)walloc((size_t)Bb * Tt * Ee * 2);         // 32 MiB
  unsigned short* Wpk  = (unsigned short*)walloc((size_t)NBLK * 2 * NKS * 64 * 16); // 12 MiB
  unsigned short* hseq = (unsigned short*)walloc((size_t)Tt * Bb * Hh * 2);         // 64 MiB rotating h
  float* hf     = (float*)walloc((size_t)Bb * Hh * 4);
  float* losses = (float*)walloc(256);
  (void)ws_size; (void)in_sizes; (void)n_in; (void)out_size;

  const long n4 = (long)Tt * Bb * Hh * 2 / 16;   // uint4 count of hseq
  fill_sentinel_kernel<<<4096, 256, 0, stream>>>((uint4*)hseq, n4);
  zero_h0_kernel<<<(Bb * Hh * 2 / 16) / 256, 256, 0, stream>>>((uint4*)hseq);
  transpose_x_kernel<<<Bb * Tt, 256, 0, stream>>>(x, xT);
  pack_w_kernel<<<NBLK * 2 * NKS, 64, 0, stream>>>(W, Wpk);

  lstm_persist<<<NBLK, 256, 0, stream>>>(xT, Wpk, bias, hseq, hf);

  classifier_kernel<<<Bb, 256, 0, stream>>>(hf, outW, outb, y, out, losses);
  finalize_kernel<<<1, 64, 0, stream>>>(losses, out);
}

// Round 10
// 5702.830 us; speedup vs baseline: 1.0159x; 1.0159x over previous
//
#include <hip/hip_runtime.h>
#include <hip/hip_bf16.h>

// SentenceClassifier: LSTM(B=64,T=512,E=512,H=1024) -> h_T @ outW + outb -> softmax/CE
// Persistent-kernel, 128 blocks x 256 thr, block owns 8 hidden units (32 gate
// cols, W slice 96KB LDS). R10: FLAG-AS-HINT + SENTINEL-AS-TRUTH. R8's chain
// had 4 serialized LLC rounds (store-ack, flag, detect, load); R9 deleted the
// flag entirely and drowned in sentinel-retry storms (consumers raced a full
// step ahead). R10 keeps the cheap flag detect but drops the vmcnt(0) ACK:
// producer stores h (agent-scope write-through), then immediately stores its
// flag -- if the flag overtakes a data line by tens of ns, the consumer's
// sentinel check catches it and the rare 8B retry fixes it. Fast path: wait
// flag -> 32x16B nontemporal burst (no L2 allocate, LLC-fresh) -> sentinel
// verify (usually clean) -> MFMA. h: rotating cold buffers pre-filled with
// bf16-NaN sentinel 0x7FC07FC0 (unreachable by f2bf of finite values); each
// address transitions sentinel->data exactly once (4B-atomic stores).
// Per-wave flag domains, no __syncthreads in t-loop, x-part W in registers.

#define Bb 64
#define Tt 512
#define Ee 512
#define Hh 1024
#define Cc 32
#define G4 4096
#define NKS 48     // (E+H)/32
#define NBLK 128
#define HIDB 8     // hid units per block
#define FPAD 32    // flag slot pad (ints) = 128B
#define SENTW 0x7FC07FC0u   // 2x bf16 NaN -- sentinel word

typedef __attribute__((ext_vector_type(8))) short short8;
typedef __attribute__((ext_vector_type(4))) float f32x4;

__device__ __forceinline__ unsigned short f2bf(float f) {
  __hip_bfloat16 h = __float2bfloat16(f);
  union { __hip_bfloat16 h; unsigned short u; } cv; cv.h = h; return cv.u;
}
static __device__ __forceinline__ float fsig(float x) { return 1.0f / (1.0f + __expf(-x)); }
static __device__ __forceinline__ float ftanhf(float x) {
  float e = __expf(-2.0f * fabsf(x));
  float t = (1.0f - e) / (1.0f + e);
  return copysignf(t, x);
}

// ---- x [B,T,E] f32 -> xT [T,B,E] bf16 (contiguous 64KB window per step) ----
__global__ __launch_bounds__(256) void transpose_x_kernel(const float* __restrict__ x,
                                                          unsigned short* __restrict__ xT) {
  const int bid = blockIdx.x;          // row*Tt + t
  const int row = bid >> 9, t = bid & (Tt - 1);
  const int e = threadIdx.x * 2;
  const float* src = x + ((size_t)row * Tt + t) * Ee + e;
  float2 v = *(const float2*)src;
  ushort2 o; o.x = f2bf(v.x); o.y = f2bf(v.y);
  *(ushort2*)(xT + ((size_t)t * Bb + row) * Ee + e) = o;
}

// ---- W [1536,4096] f32 -> per-block B-frag-packed bf16 --------------------
__global__ __launch_bounds__(64) void pack_w_kernel(const float* __restrict__ W,
                                                    unsigned short* __restrict__ Wpk) {
  const int fid = blockIdx.x;          // blk*96 + tau*48 + ks
  const int l = threadIdx.x;
  const int blk = fid / 96, rem = fid % 96;
  const int tau = rem / 48, ks = rem % 48;
  const int c = l & 15;
  const int col = (2 * tau + (c >> 3)) * Hh + blk * HIDB + (c & 7);
  const int k0 = ks * 32 + (l >> 4) * 8;
  short8 v;
#pragma unroll
  for (int i = 0; i < 8; i++) v[i] = (short)f2bf(W[(size_t)(k0 + i) * G4 + col]);
  *(short8*)(Wpk + ((size_t)fid * 64 + l) * 8) = v;
}

// ---- pre-fill all h buffers with sentinel ---------------------------------
__global__ __launch_bounds__(256) void fill_sentinel_kernel(uint4* __restrict__ p, long n4) {
  long i = (long)blockIdx.x * 256 + threadIdx.x;
  const long stride = (long)gridDim.x * 256;
  uint4 v; v.x = SENTW; v.y = SENTW; v.z = SENTW; v.w = SENTW;
  for (; i < n4; i += stride) p[i] = v;
}

// ---- zero h buffer 0 (t=0 input) + flag slots (runs after sentinel fill) ---
__global__ __launch_bounds__(256) void init_state_kernel(unsigned short* __restrict__ h0,
                                                         int* __restrict__ flg) {
  int i = blockIdx.x * 256 + threadIdx.x;   // grid covers Bb*Hh
  h0[i] = 0;
  if (i < 4 * NBLK * FPAD) flg[i] = 0;      // 512 padded flag slots
}

// ---- persistent LSTM kernel ----------------------------------------------
__global__ __launch_bounds__(256, 1) void lstm_persist(
    const unsigned short* __restrict__ xT, const unsigned short* __restrict__ Wpk,
    const float* __restrict__ bias,
    unsigned short* __restrict__ hseq,   // Tt buffers, block-major [bc][row][8hid]
    float* __restrict__ h_f32, int* __restrict__ flg) {
  __shared__ short8 Wl[2 * NKS * 64];       // 96 KiB
  const int bc = blockIdx.x;
  const int tid = threadIdx.x;

  { // one-time: W slice -> LDS (linear 96KB copy)
    const short8* src = (const short8*)Wpk + (size_t)bc * (2 * NKS * 64);
    for (int i = tid; i < 2 * NKS * 64; i += 256) Wl[i] = src[i];
  }

  const int wv = tid >> 6, ln = tid & 63;
  const int c = ln & 15, kg = ln >> 4;
  const int arow = wv * 16 + c;        // A-frag row = batch index
  const int rbase = wv * 16 + kg * 4;  // D rows (m89 layout: row=(l>>4)*4+r, col=l&15)
  const int hid = bc * HIDB + (c & 7);
  const bool lo = (c < 8);
  const float bi = bias[hid], bj = bias[Hh + hid];
  const float bff = bias[2 * Hh + hid], bo = bias[3 * Hh + hid];
  float cstate[4] = {0.f, 0.f, 0.f, 0.f};

  __syncthreads();                      // W in LDS ready (only barrier in kernel)

  const short8* W0 = Wl;                // tile0 (gates i,j)
  const short8* W1 = Wl + NKS * 64;     // tile1 (gates f,o)

  // x-part W fragments: same LDS addresses every step -> hoist to registers
  short8 wx0[16], wx1[16];
#pragma unroll
  for (int kk = 0; kk < 16; kk++) { wx0[kk] = W0[kk * 64 + ln]; wx1[kk] = W1[kk * 64 + ln]; }

  int* flgw = flg + wv * NBLK * FPAD;   // own wave's flag domain
  int* myslot = flgw + bc * FPAD;
  int* slot0 = flgw + ln * FPAD;        // wait-all: 2 slots per lane
  int* slot1 = flgw + (ln + 64) * FPAD;

  f32x4 xa0, xa1;
  // x-part for t=0
  {
    const unsigned short* xr = xT + ((size_t)0 * Bb + arow) * Ee + kg * 8;
    f32x4 a0 = {0.f,0.f,0.f,0.f}, a1 = {0.f,0.f,0.f,0.f};
#pragma unroll
    for (int kk = 0; kk < 16; kk++) {
      short8 a = *(const short8*)(xr + kk * 32);
      a0 = __builtin_amdgcn_mfma_f32_16x16x32_bf16(a, wx0[kk], a0, 0, 0, 0);
      a1 = __builtin_amdgcn_mfma_f32_16x16x32_bf16(a, wx1[kk], a1, 0, 0, 0);
    }
    xa0 = a0; xa1 = a1;
  }

  for (int t = 0; t < Tt; t++) {
    // ---- detect hint: own wave-plane producers flagged step t (no ack behind
    // this flag -- it can lead the data by tens of ns; sentinel covers that).
    for (;;) {
      int v0 = __hip_atomic_load(slot0, __ATOMIC_RELAXED, __HIP_MEMORY_SCOPE_AGENT);
      int v1 = __hip_atomic_load(slot1, __ATOMIC_RELAXED, __HIP_MEMORY_SCOPE_AGENT);
      if (v0 >= t && v1 >= t) break;
      __builtin_amdgcn_s_sleep(1);
    }
    asm volatile("" ::: "memory");      // no hoist of h loads above the wait

    // ---- nontemporal burst: 32 independent 16B h-loads (no L2 allocate ->
    // LLC-fresh; staleness structurally impossible).
    const unsigned short* hr = hseq + (size_t)t * (NBLK * Bb * HIDB) + kg * 512 + arow * 8;
    short8 f[32];
#pragma unroll
    for (int kk = 0; kk < 32; kk++)
      f[kk] = __builtin_nontemporal_load((const short8*)(hr + kk * 2048));
    asm volatile("s_waitcnt vmcnt(0)" ::: "memory");
    __builtin_amdgcn_sched_barrier(0);

    // ---- sentinel verify (fast path: zero misses) + rare targeted retry
    unsigned miss = 0;
#pragma unroll
    for (int kk = 0; kk < 32; kk++) {
      union { short8 s; unsigned u[4]; } q; q.s = f[kk];
      if ((q.u[0] == SENTW) | (q.u[1] == SENTW) | (q.u[2] == SENTW) | (q.u[3] == SENTW))
        miss |= (1u << kk);
    }
    while (__any(miss)) {
      __builtin_amdgcn_s_sleep(1);
#pragma unroll
      for (int kk = 0; kk < 32; kk++) {
        if (miss & (1u << kk)) {
          const unsigned long long* pq = (const unsigned long long*)(hr + kk * 2048);
          unsigned long long w0 = __hip_atomic_load(pq,     __ATOMIC_RELAXED, __HIP_MEMORY_SCOPE_AGENT);
          unsigned long long w1 = __hip_atomic_load(pq + 1, __ATOMIC_RELAXED, __HIP_MEMORY_SCOPE_AGENT);
          union { unsigned long long q[2]; short8 s; unsigned u[4]; } nb;
          nb.q[0] = w0; nb.q[1] = w1;
          if (!((nb.u[0] == SENTW) | (nb.u[1] == SENTW) |
                (nb.u[2] == SENTW) | (nb.u[3] == SENTW))) {
            f[kk] = nb.s;
            miss &= ~(1u << kk);
          }
        }
      }
    }

    f32x4 a0 = xa0, a1 = xa1;
#pragma unroll
    for (int kk = 0; kk < 32; kk++) {
      a0 = __builtin_amdgcn_mfma_f32_16x16x32_bf16(f[kk], W0[(16 + kk) * 64 + ln], a0, 0, 0, 0);
      a1 = __builtin_amdgcn_mfma_f32_16x16x32_bf16(f[kk], W1[(16 + kk) * 64 + ln], a1, 0, 0, 0);
    }

    // cell update: tile0 lane c<8 holds i (c>=8: j), tile1 holds f (o). One
    // shfl_xor(8) gives each lane all 4 gates; lane pair (c, c^8) redundant.
    float hnew[4];
#pragma unroll
    for (int r = 0; r < 4; r++) {
      const float p0 = a0[r], p1 = a1[r];
      const float s0 = __shfl_xor(p0, 8), s1 = __shfl_xor(p1, 8);
      const float gi = (lo ? p0 : s0) + bi;
      const float gj = (lo ? s0 : p0) + bj;
      const float gf = (lo ? p1 : s1) + bff;
      const float go = (lo ? s1 : p1) + bo;
      const float cn = cstate[r] * fsig(gf + 1.0f) + fsig(gi) * ftanhf(gj);
      cstate[r] = cn;
      hnew[r] = ftanhf(cn) * fsig(go);
    }

    if (t < Tt - 1) {
      // pack hid pairs into 4B words; even-lo lanes store agent-coherent
      // (write-through). NO ack: flag follows immediately; sentinel validates.
      unsigned int hw[4];
#pragma unroll
      for (int r = 0; r < 4; r++) {
        unsigned short us = f2bf(hnew[r]);
        unsigned short ps = (unsigned short)__shfl_xor((int)us, 1);
        hw[r] = (unsigned)us | ((unsigned)ps << 16);
      }
      unsigned int* hob = (unsigned int*)hseq + (size_t)(t + 1) * (NBLK * Bb * HIDB / 2)
                          + bc * (Bb * HIDB / 2);
      if (lo && !(c & 1)) {
#pragma unroll
        for (int r = 0; r < 4; r++)
          __hip_atomic_store(hob + (rbase + r) * 4 + ((c & 7) >> 1),
                             hw[r], __ATOMIC_RELAXED, __HIP_MEMORY_SCOPE_AGENT);
      }
      if (ln == 0)                      // hint flag: issued right behind data
        __hip_atomic_store(myslot, t + 1, __ATOMIC_RELAXED, __HIP_MEMORY_SCOPE_AGENT);
      // x-part MFMAs for t+1 (h-independent, W from registers) while stores fly
      {
        const unsigned short* xr = xT + ((size_t)(t + 1) * Bb + arow) * Ee + kg * 8;
        f32x4 b0 = {0.f,0.f,0.f,0.f}, b1 = {0.f,0.f,0.f,0.f};
#pragma unroll
        for (int kk = 0; kk < 16; kk++) {
          short8 a = *(const short8*)(xr + kk * 32);
          b0 = __builtin_amdgcn_mfma_f32_16x16x32_bf16(a, wx0[kk], b0, 0, 0, 0);
          b1 = __builtin_amdgcn_mfma_f32_16x16x32_bf16(a, wx1[kk], b1, 0, 0, 0);
        }
        xa0 = b0; xa1 = b1;
      }
    } else {
      if (lo) {
#pragma unroll
        for (int r = 0; r < 4; r++) h_f32[(rbase + r) * Hh + hid] = hnew[r];
      }
    }
  }
}

// ---- classifier: pred = h @ outW + outb, softmax, per-row CE --------------
__global__ __launch_bounds__(256) void classifier_kernel(
    const float* __restrict__ h, const float* __restrict__ outW,
    const float* __restrict__ outb, const float* __restrict__ y,
    float* __restrict__ out, float* __restrict__ losses) {
  __shared__ float red[256];
  const int brow = blockIdx.x;
  const int tid = threadIdx.x;
  const int cc = tid & 31;
  const int part = tid >> 5;
  const float* hr = h + brow * Hh;
  float p = 0.f;
  for (int k = part * 128; k < part * 128 + 128; k++)
    p += hr[k] * outW[k * Cc + cc];
  red[tid] = p;
  __syncthreads();
  if (part < 4) red[tid] += red[tid + 128];
  __syncthreads();
  if (part < 2) red[tid] += red[tid + 64];
  __syncthreads();
  if (part < 1) red[tid] += red[tid + 32];
  __syncthreads();
  if (tid < 32) {
    const float logit = red[tid] + outb[tid];
    float m = logit;
    for (int off = 16; off >= 1; off >>= 1) m = fmaxf(m, __shfl_xor(m, off));
    const float e = __expf(logit - m);
    float s = e;
    for (int off = 16; off >= 1; off >>= 1) s += __shfl_xor(s, off);
    out[brow * Cc + tid] = logit;
    out[Bb * Cc + brow * Cc + tid] = e / s;
    const float logp = (logit - m) - __logf(s);
    float contrib = y[brow * Cc + tid] * logp;
    for (int off = 16; off >= 1; off >>= 1) contrib += __shfl_xor(contrib, off);
    if (tid == 0) losses[brow] = -contrib;
  }
}

__global__ __launch_bounds__(64) void finalize_kernel(const float* __restrict__ losses,
                                                      float* __restrict__ out) {
  float v = losses[threadIdx.x];
  for (int off = 32; off >= 1; off >>= 1) v += __shfl_down(v, off);
  if (threadIdx.x == 0) out[2 * Bb * Cc] = v * (1.0f / Bb);
}

extern "C" void kernel_launch(void* const* d_in, const int* in_sizes, int n_in,
                              void* d_out, int out_size, void* d_ws, size_t ws_size,
                              hipStream_t stream) {
  const float* x    = (const float*)d_in[0];
  const float* y    = (const float*)d_in[1];
  // d_in[2] = seqlen (unused)
  const float* W    = (const float*)d_in[3];
  const float* bias = (const float*)d_in[4];
  const float* outW = (const float*)d_in[5];
  const float* outb = (const float*)d_in[6];
  float* out = (float*)d_out;

  char* wsp = (char*)d_ws;
  size_t off = 0;
  auto walloc = [&](size_t bytes) -> void* {
    void* p = wsp + off;
    off += (bytes + 255) & ~(size_t)255;
    return p;
  };
  unsigned short* xT   = (unsigned short*)walloc((size_t)Bb * Tt * Ee * 2);         // 32 MiB
  unsigned short* Wpk  = (unsigned short*)walloc((size_t)NBLK * 2 * NKS * 64 * 16); // 12 MiB
  unsigned short* hseq = (unsigned short*)walloc((size_t)Tt * Bb * Hh * 2);         // 64 MiB rotating h
  float* hf     = (float*)walloc((size_t)Bb * Hh * 4);
  float* losses = (float*)walloc(256);
  int* flg      = (int*)walloc(4 * NBLK * FPAD * 4);                                // 64 KiB flags
  (void)ws_size; (void)in_sizes; (void)n_in; (void)out_size;

  const long n4 = (long)Tt * Bb * Hh * 2 / 16;   // uint4 count of hseq
  fill_sentinel_kernel<<<4096, 256, 0, stream>>>((uint4*)hseq, n4);
  init_state_kernel<<<(Bb * Hh) / 256, 256, 0, stream>>>(hseq, flg);
  transpose_x_kernel<<<Bb * Tt, 256, 0, stream>>>(x, xT);
  pack_w_kernel<<<NBLK * 2 * NKS, 64, 0, stream>>>(W, Wpk);

  lstm_persist<<<NBLK, 256, 0, stream>>>(xT, Wpk, bias, hseq, hf, flg);

  classifier_kernel<<<Bb, 256, 0, stream>>>(hf, outW, outb, y, out, losses);
  finalize_kernel<<<1, 64, 0, stream>>>(losses, out);
}

// Round 11
// 3508.283 us; speedup vs baseline: 1.6514x; 1.6255x over previous
//
#include <hip/hip_runtime.h>
#include <hip/hip_bf16.h>

// SentenceClassifier: LSTM(B=64,T=512,E=512,H=1024) -> h_T @ outW + outb -> softmax/CE
// Persistent-kernel, 128 worker blocks x 256 thr + 1 AGGREGATOR block.
// R11: HIERARCHICAL DETECT. R8's consumers each re-polled 128 flag slots with
// uncached agent loads (~200K req/us device-wide, ~5-10x the LLC small-request
// service rate) -- the poll storm throttled every other LLC transaction and
// explains the ~7us/step plateau across R3-R8. Now block 128 (no LDS) runs 4
// waves; wave w min-reduces plane w's 128 producer flags in a tight loop and
// publishes a single epoch[w]; consumers poll ONE wave-uniform line. Detect
// traffic drops ~60x. Chain adds one LLC hop. Everything else is R8 verbatim:
// rotating cold h buffers (block-major), agent write-through stores ->
// vmcnt(0) ack -> flag; forced 32x16B cached load burst on cold addresses;
// x-part W in registers; x-GEMM in the detect shadow; no __syncthreads in
// the t-loop.

#define Bb 64
#define Tt 512
#define Ee 512
#define Hh 1024
#define Cc 32
#define G4 4096
#define NKS 48     // (E+H)/32
#define NBLK 128
#define HIDB 8     // hid units per block
#define FPAD 32    // flag slot pad (ints) = 128B

typedef __attribute__((ext_vector_type(8))) short short8;
typedef __attribute__((ext_vector_type(4))) float f32x4;

__device__ __forceinline__ unsigned short f2bf(float f) {
  __hip_bfloat16 h = __float2bfloat16(f);
  union { __hip_bfloat16 h; unsigned short u; } cv; cv.h = h; return cv.u;
}
static __device__ __forceinline__ float fsig(float x) { return 1.0f / (1.0f + __expf(-x)); }
static __device__ __forceinline__ float ftanhf(float x) {
  float e = __expf(-2.0f * fabsf(x));
  float t = (1.0f - e) / (1.0f + e);
  return copysignf(t, x);
}

// ---- x [B,T,E] f32 -> xT [T,B,E] bf16 (contiguous 64KB window per step) ----
__global__ __launch_bounds__(256) void transpose_x_kernel(const float* __restrict__ x,
                                                          unsigned short* __restrict__ xT) {
  const int bid = blockIdx.x;          // row*Tt + t
  const int row = bid >> 9, t = bid & (Tt - 1);
  const int e = threadIdx.x * 2;
  const float* src = x + ((size_t)row * Tt + t) * Ee + e;
  float2 v = *(const float2*)src;
  ushort2 o; o.x = f2bf(v.x); o.y = f2bf(v.y);
  *(ushort2*)(xT + ((size_t)t * Bb + row) * Ee + e) = o;
}

// ---- W [1536,4096] f32 -> per-block B-frag-packed bf16 --------------------
__global__ __launch_bounds__(64) void pack_w_kernel(const float* __restrict__ W,
                                                    unsigned short* __restrict__ Wpk) {
  const int fid = blockIdx.x;          // blk*96 + tau*48 + ks
  const int l = threadIdx.x;
  const int blk = fid / 96, rem = fid % 96;
  const int tau = rem / 48, ks = rem % 48;
  const int c = l & 15;
  const int col = (2 * tau + (c >> 3)) * Hh + blk * HIDB + (c & 7);
  const int k0 = ks * 32 + (l >> 4) * 8;
  short8 v;
#pragma unroll
  for (int i = 0; i < 8; i++) v[i] = (short)f2bf(W[(size_t)(k0 + i) * G4 + col]);
  *(short8*)(Wpk + ((size_t)fid * 64 + l) * 8) = v;
}

// ---- zero h buffer 0 + flag/epoch state -----------------------------------
__global__ __launch_bounds__(256) void init_state_kernel(unsigned short* __restrict__ h0,
                                                         int* __restrict__ flg) {
  int i = blockIdx.x * 256 + threadIdx.x;   // grid covers Bb*Hh
  h0[i] = 0;
  if (i < 4 * NBLK * FPAD + 4 * FPAD) flg[i] = 0;   // 512 flag slots + 4 epochs
}

// ---- persistent LSTM kernel (+ aggregator block) --------------------------
__global__ __launch_bounds__(256, 1) void lstm_persist(
    const unsigned short* __restrict__ xT, const unsigned short* __restrict__ Wpk,
    const float* __restrict__ bias,
    unsigned short* __restrict__ hseq,   // Tt buffers, block-major [bc][row][8hid]
    float* __restrict__ h_f32, int* __restrict__ flg) {
  const int bc = blockIdx.x;
  const int tid = threadIdx.x;
  const int wv = tid >> 6, ln = tid & 63;

  int* epoch = flg + 4 * NBLK * FPAD;   // 4 epoch lines (128B apart)

  // ---------------- aggregator block: min-reduce flags -> epoch ------------
  if (bc == NBLK) {
    int* flgw2 = flg + wv * NBLK * FPAD;
    int* ep = epoch + wv * FPAD;
    int cur = 0;
    while (cur < Tt - 1) {
      int a = __hip_atomic_load(flgw2 + ln * FPAD,        __ATOMIC_RELAXED, __HIP_MEMORY_SCOPE_AGENT);
      int b = __hip_atomic_load(flgw2 + (ln + 64) * FPAD, __ATOMIC_RELAXED, __HIP_MEMORY_SCOPE_AGENT);
      int m = a < b ? a : b;
#pragma unroll
      for (int off = 32; off >= 1; off >>= 1) {
        int o = __shfl_xor(m, off);
        m = o < m ? o : m;
      }
      if (m > cur) {
        cur = m;
        if (ln == 0)
          __hip_atomic_store(ep, cur, __ATOMIC_RELAXED, __HIP_MEMORY_SCOPE_AGENT);
      }
    }
    return;
  }

  // ---------------- worker blocks ------------------------------------------
  __shared__ short8 Wl[2 * NKS * 64];       // 96 KiB

  { // one-time: W slice -> LDS (linear 96KB copy)
    const short8* src = (const short8*)Wpk + (size_t)bc * (2 * NKS * 64);
    for (int i = tid; i < 2 * NKS * 64; i += 256) Wl[i] = src[i];
  }

  const int c = ln & 15, kg = ln >> 4;
  const int arow = wv * 16 + c;        // A-frag row = batch index
  const int rbase = wv * 16 + kg * 4;  // D rows (m89 layout: row=(l>>4)*4+r, col=l&15)
  const int hid = bc * HIDB + (c & 7);
  const bool lo = (c < 8);
  const float bi = bias[hid], bj = bias[Hh + hid];
  const float bff = bias[2 * Hh + hid], bo = bias[3 * Hh + hid];
  float cstate[4] = {0.f, 0.f, 0.f, 0.f};

  __syncthreads();                      // W in LDS ready (only barrier in kernel)

  const short8* W0 = Wl;                // tile0 (gates i,j)
  const short8* W1 = Wl + NKS * 64;     // tile1 (gates f,o)

  // x-part W fragments: same LDS addresses every step -> hoist to registers
  short8 wx0[16], wx1[16];
#pragma unroll
  for (int kk = 0; kk < 16; kk++) { wx0[kk] = W0[kk * 64 + ln]; wx1[kk] = W1[kk * 64 + ln]; }

  int* flgw = flg + wv * NBLK * FPAD;   // own wave's flag domain
  int* myslot = flgw + bc * FPAD;
  int* myep = epoch + wv * FPAD;        // single detect line for this plane

  f32x4 xa0, xa1;
  // x-part for t=0
  {
    const unsigned short* xr = xT + ((size_t)0 * Bb + arow) * Ee + kg * 8;
    f32x4 a0 = {0.f,0.f,0.f,0.f}, a1 = {0.f,0.f,0.f,0.f};
#pragma unroll
    for (int kk = 0; kk < 16; kk++) {
      short8 a = *(const short8*)(xr + kk * 32);
      a0 = __builtin_amdgcn_mfma_f32_16x16x32_bf16(a, wx0[kk], a0, 0, 0, 0);
      a1 = __builtin_amdgcn_mfma_f32_16x16x32_bf16(a, wx1[kk], a1, 0, 0, 0);
    }
    xa0 = a0; xa1 = a1;
  }

  for (int t = 0; t < Tt; t++) {
    // ---- detect: single epoch line (aggregator guarantees all 128 flags >= t,
    // and flags are acked behind the h data -> data visible in LLC).
    while (__hip_atomic_load(myep, __ATOMIC_RELAXED, __HIP_MEMORY_SCOPE_AGENT) < t)
      __builtin_amdgcn_s_sleep(1);
    asm volatile("" ::: "memory");      // no hoist of h loads above the wait

    // ---- FORCED deep burst: all 32 independent 16B h-loads issued, then one
    // drain; sched_barrier pins MFMAs below (rule #18).
    const unsigned short* hr = hseq + (size_t)t * (NBLK * Bb * HIDB) + kg * 512 + arow * 8;
    short8 f[32];
#pragma unroll
    for (int kk = 0; kk < 32; kk++) f[kk] = *(const short8*)(hr + kk * 2048);
    asm volatile("s_waitcnt vmcnt(0)" ::: "memory");
    __builtin_amdgcn_sched_barrier(0);

    f32x4 a0 = xa0, a1 = xa1;
#pragma unroll
    for (int kk = 0; kk < 32; kk++) {
      a0 = __builtin_amdgcn_mfma_f32_16x16x32_bf16(f[kk], W0[(16 + kk) * 64 + ln], a0, 0, 0, 0);
      a1 = __builtin_amdgcn_mfma_f32_16x16x32_bf16(f[kk], W1[(16 + kk) * 64 + ln], a1, 0, 0, 0);
    }

    // cell update: tile0 lane c<8 holds i (c>=8: j), tile1 holds f (o). One
    // shfl_xor(8) gives each lane all 4 gates; lane pair (c, c^8) redundant.
    float hnew[4];
#pragma unroll
    for (int r = 0; r < 4; r++) {
      const float p0 = a0[r], p1 = a1[r];
      const float s0 = __shfl_xor(p0, 8), s1 = __shfl_xor(p1, 8);
      const float gi = (lo ? p0 : s0) + bi;
      const float gj = (lo ? s0 : p0) + bj;
      const float gf = (lo ? p1 : s1) + bff;
      const float go = (lo ? s1 : p1) + bo;
      const float cn = cstate[r] * fsig(gf + 1.0f) + fsig(gi) * ftanhf(gj);
      cstate[r] = cn;
      hnew[r] = ftanhf(cn) * fsig(go);
    }

    if (t < Tt - 1) {
      // pack hid pairs into 4B words; even-lo lanes store agent-coherent
      // (write-through). Block-major: wave-private 256B.
      unsigned int hw[4];
#pragma unroll
      for (int r = 0; r < 4; r++) {
        unsigned short us = f2bf(hnew[r]);
        unsigned short ps = (unsigned short)__shfl_xor((int)us, 1);
        hw[r] = (unsigned)us | ((unsigned)ps << 16);
      }
      unsigned int* hob = (unsigned int*)hseq + (size_t)(t + 1) * (NBLK * Bb * HIDB / 2)
                          + bc * (Bb * HIDB / 2);
      if (lo && !(c & 1)) {
#pragma unroll
        for (int r = 0; r < 4; r++)
          __hip_atomic_store(hob + (rbase + r) * 4 + ((c & 7) >> 1),
                             hw[r], __ATOMIC_RELAXED, __HIP_MEMORY_SCOPE_AGENT);
      }
      // wave-local drain: h stores acked at coherence point before flag store
      asm volatile("s_waitcnt vmcnt(0)" ::: "memory");
      if (ln == 0)
        __hip_atomic_store(myslot, t + 1, __ATOMIC_RELAXED, __HIP_MEMORY_SCOPE_AGENT);
      // x-part MFMAs for t+1 (h-independent, W from registers) in detect shadow
      {
        const unsigned short* xr = xT + ((size_t)(t + 1) * Bb + arow) * Ee + kg * 8;
        f32x4 b0 = {0.f,0.f,0.f,0.f}, b1 = {0.f,0.f,0.f,0.f};
#pragma unroll
        for (int kk = 0; kk < 16; kk++) {
          short8 a = *(const short8*)(xr + kk * 32);
          b0 = __builtin_amdgcn_mfma_f32_16x16x32_bf16(a, wx0[kk], b0, 0, 0, 0);
          b1 = __builtin_amdgcn_mfma_f32_16x16x32_bf16(a, wx1[kk], b1, 0, 0, 0);
        }
        xa0 = b0; xa1 = b1;
      }
    } else {
      if (lo) {
#pragma unroll
        for (int r = 0; r < 4; r++) h_f32[(rbase + r) * Hh + hid] = hnew[r];
      }
    }
  }
}

// ---- classifier: pred = h @ outW + outb, softmax, per-row CE --------------
__global__ __launch_bounds__(256) void classifier_kernel(
    const float* __restrict__ h, const float* __restrict__ outW,
    const float* __restrict__ outb, const float* __restrict__ y,
    float* __restrict__ out, float* __restrict__ losses) {
  __shared__ float red[256];
  const int brow = blockIdx.x;
  const int tid = threadIdx.x;
  const int cc = tid & 31;
  const int part = tid >> 5;
  const float* hr = h + brow * Hh;
  float p = 0.f;
  for (int k = part * 128; k < part * 128 + 128; k++)
    p += hr[k] * outW[k * Cc + cc];
  red[tid] = p;
  __syncthreads();
  if (part < 4) red[tid] += red[tid + 128];
  __syncthreads();
  if (part < 2) red[tid] += red[tid + 64];
  __syncthreads();
  if (part < 1) red[tid] += red[tid + 32];
  __syncthreads();
  if (tid < 32) {
    const float logit = red[tid] + outb[tid];
    float m = logit;
    for (int off = 16; off >= 1; off >>= 1) m = fmaxf(m, __shfl_xor(m, off));
    const float e = __expf(logit - m);
    float s = e;
    for (int off = 16; off >= 1; off >>= 1) s += __shfl_xor(s, off);
    out[brow * Cc + tid] = logit;
    out[Bb * Cc + brow * Cc + tid] = e / s;
    const float logp = (logit - m) - __logf(s);
    float contrib = y[brow * Cc + tid] * logp;
    for (int off = 16; off >= 1; off >>= 1) contrib += __shfl_xor(contrib, off);
    if (tid == 0) losses[brow] = -contrib;
  }
}

__global__ __launch_bounds__(64) void finalize_kernel(const float* __restrict__ losses,
                                                      float* __restrict__ out) {
  float v = losses[threadIdx.x];
  for (int off = 32; off >= 1; off >>= 1) v += __shfl_down(v, off);
  if (threadIdx.x == 0) out[2 * Bb * Cc] = v * (1.0f / Bb);
}

extern "C" void kernel_launch(void* const* d_in, const int* in_sizes, int n_in,
                              void* d_out, int out_size, void* d_ws, size_t ws_size,
                              hipStream_t stream) {
  const float* x    = (const float*)d_in[0];
  const float* y    = (const float*)d_in[1];
  // d_in[2] = seqlen (unused)
  const float* W    = (const float*)d_in[3];
  const float* bias = (const float*)d_in[4];
  const float* outW = (const float*)d_in[5];
  const float* outb = (const float*)d_in[6];
  float* out = (float*)d_out;

  char* wsp = (char*)d_ws;
  size_t off = 0;
  auto walloc = [&](size_t bytes) -> void* {
    void* p = wsp + off;
    off += (bytes + 255) & ~(size_t)255;
    return p;
  };
  unsigned short* xT   = (unsigned short*)walloc((size_t)Bb * Tt * Ee * 2);         // 32 MiB
  unsigned short* Wpk  = (unsigned short*)walloc((size_t)NBLK * 2 * NKS * 64 * 16); // 12 MiB
  unsigned short* hseq = (unsigned short*)walloc((size_t)Tt * Bb * Hh * 2);         // 64 MiB rotating h
  float* hf     = (float*)walloc((size_t)Bb * Hh * 4);
  float* losses = (float*)walloc(256);
  int* flg      = (int*)walloc((4 * NBLK * FPAD + 4 * FPAD) * 4);                   // flags + epochs
  (void)ws_size; (void)in_sizes; (void)n_in; (void)out_size;

  transpose_x_kernel<<<Bb * Tt, 256, 0, stream>>>(x, xT);
  pack_w_kernel<<<NBLK * 2 * NKS, 64, 0, stream>>>(W, Wpk);
  init_state_kernel<<<(Bb * Hh) / 256, 256, 0, stream>>>(hseq, flg);

  lstm_persist<<<NBLK + 1, 256, 0, stream>>>(xT, Wpk, bias, hseq, hf, flg);

  classifier_kernel<<<Bb, 256, 0, stream>>>(hf, outW, outb, y, out, losses);
  finalize_kernel<<<1, 64, 0, stream>>>(losses, out);
}